// Round 3
// baseline (105.969 us; speedup 1.0000x reference)
//
#include <hip/hip_runtime.h>

#ifndef __has_builtin
#define __has_builtin(x) 0
#endif

#if __has_builtin(__builtin_amdgcn_exp2f)
#define EXP2F(x) __builtin_amdgcn_exp2f(x)
#else
#define EXP2F(x) exp2f(x)
#endif

#if __has_builtin(__builtin_amdgcn_rcpf)
#define RCPF(x) __builtin_amdgcn_rcpf(x)
#else
#define RCPF(x) (1.0f / (x))
#endif

#if __has_builtin(__builtin_amdgcn_global_load_lds)
#define USE_GLOAD_LDS 1
#else
#define USE_GLOAD_LDS 0
#endif

namespace {

constexpr int kB = 65536;
constexpr int kT = 50;
constexpr int kI = 2;
constexpr int kH = 20;
constexpr int kO = 2;
constexpr int kCT = 5;    // timesteps per staged chunk
constexpr int kNC = 10;   // chunks (kCT*kNC == kT)
constexpr int kGB = 64;   // batch elements per block

#if USE_GLOAD_LDS
typedef const __attribute__((address_space(1))) void* gas_ptr_t;
typedef __attribute__((address_space(3))) void* las_ptr_t;
#endif

__device__ __forceinline__ float fast_tanh(float v) {
    const float p = EXP2F(v * 2.8853900817779268f);
    return fmaf(-2.0f, RCPF(p + 1.0f), 1.0f);
}

// Intra-quad lane exchange via DPP quad_perm (pure VALU).
#if __has_builtin(__builtin_amdgcn_mov_dpp)
template <int CTRL>
__device__ __forceinline__ float fqp(float v) {
    return __int_as_float(
        __builtin_amdgcn_mov_dpp(__float_as_int(v), CTRL, 0xF, 0xF, true));
}
#else
template <int CTRL>
__device__ __forceinline__ float fqp(float v) {
    constexpr int d = (CTRL == 0xB1) ? 1 : (CTRL == 0x4E) ? 2 : 3;
    return __shfl_xor(v, d);
}
#endif

// 4 threads per batch element; thread sub owns hidden rows 4*i+sub.
// Mask is staged per 5-timestep chunk into LDS with fully-coalesced
// 1KB wave loads (400B burst per batch stream), consumed via ds_read_b32
// (stride-100-float layout -> only free 2-way bank aliasing).
__global__ __launch_bounds__(256)
__attribute__((amdgpu_waves_per_eu(2, 3)))
void dprnn_kernel(
    const float* __restrict__ x, const float* __restrict__ W_ih,
    const float* __restrict__ W_hh, const float* __restrict__ b_ih,
    const float* __restrict__ b_hh, const float* __restrict__ W_out,
    const float* __restrict__ b_out, const float* __restrict__ mask,
    float* __restrict__ out)
{
    __shared__ __align__(16) float sm[kGB * kCT * kH + kGB * kCT * kO];
    float* lds_m = sm;                      // [64][100] floats, 25600 B
    float* lds_o = sm + kGB * kCT * kH;     // [64][10]  floats,  2560 B

    const int tidx = threadIdx.x;
    const int gl   = tidx >> 2;   // local batch element 0..63
    const int sub  = tidx & 3;    // quarter of H owned
    const int Wv   = tidx >> 6;   // wave id 0..3
    const int lane = tidx & 63;
    const size_t g0 = (size_t)blockIdx.x * kGB;

    // ---- weights into registers (column-permuted for DPP gather) ----
    float w[5][5][4];
    float wi0[5], wi1[5], bia[5], wo0[5], wo1[5];
#pragma unroll
    for (int i = 0; i < 5; ++i) {
        const int row = 4 * i + sub;
#pragma unroll
        for (int r = 0; r < 5; ++r)
#pragma unroll
            for (int d = 0; d < 4; ++d)
                w[i][r][d] = W_hh[row * kH + 4 * r + (sub ^ d)];
        wi0[i] = W_ih[row * kI + 0];
        wi1[i] = W_ih[row * kI + 1];
        bia[i] = b_ih[row] + b_hh[row];
        wo0[i] = W_out[row];
        wo1[i] = W_out[kH + row];
    }
    const float bo0 = b_out[0];
    const float bo1 = b_out[1];

    // ---- mask staging: 1600 x 16B per chunk = 25 wave-instrs of 1KB ----
    // flat v in [0,1600): g = v/25, w16 = v%25 ; LDS byte = v*16 (linear)
    const char* mask_blk = (const char*)mask + g0 * (size_t)(kT * kH * 4);
    uint32_t srcoff[7];
#pragma unroll
    for (int i = 0; i < 7; ++i) {
        const int v  = (i < 6) ? ((i * 4 + Wv) * 64 + lane) : (1536 + lane);
        const int gv = v / 25;
        const int wv = v - gv * 25;
        srcoff[i] = (uint32_t)(gv * (kT * kH * 4) + wv * 16);
    }

    auto stage_mask = [&](int c) {
        const char* src = mask_blk + c * (kCT * kH * 4);
#if USE_GLOAD_LDS
#pragma unroll
        for (int i = 0; i < 6; ++i)
            __builtin_amdgcn_global_load_lds(
                (gas_ptr_t)(const void*)(src + srcoff[i]),
                (las_ptr_t)(void*)((char*)sm + (i * 4 + Wv) * 1024),
                16, 0, 0);
        if (Wv == 0)
            __builtin_amdgcn_global_load_lds(
                (gas_ptr_t)(const void*)(src + srcoff[6]),
                (las_ptr_t)(void*)((char*)sm + 24576),
                16, 0, 0);
#else
        float4 t[7];
#pragma unroll
        for (int i = 0; i < 6; ++i)
            t[i] = *(const float4*)(src + srcoff[i]);
        if (Wv == 0) t[6] = *(const float4*)(src + srcoff[6]);
#pragma unroll
        for (int i = 0; i < 6; ++i)
            *(float4*)((char*)sm + ((i * 4 + Wv) * 64 + lane) * 16) = t[i];
        if (Wv == 0) *(float4*)((char*)sm + (1536 + lane) * 16) = t[6];
#endif
    };

    // ---- x chunk in registers (quad-redundant loads dedupe in L1) ----
    const float* xg = x + (g0 + gl) * (kT * kI);
    float2 xA[kCT];
    auto load_x = [&](int c) {
#pragma unroll
        for (int j = 0; j < kCT; ++j)
            xA[j] = *(const float2*)(xg + c * (kCT * kI) + j * kI);
    };

    float h[5] = {0.f, 0.f, 0.f, 0.f, 0.f};
    const int mbase = gl * (kCT * kH) + sub;

    auto step = [&](int j) {
        float m[5];
#pragma unroll
        for (int r = 0; r < 5; ++r)
            m[r] = lds_m[mbase + j * kH + 4 * r];
        const float x0 = xA[j].x, x1 = xA[j].y;
        float acc[5];
#pragma unroll
        for (int i = 0; i < 5; ++i)
            acc[i] = fmaf(wi0[i], x0, fmaf(wi1[i], x1, bia[i]));
#pragma unroll
        for (int r = 0; r < 5; ++r) {
            const float v0 = h[r];
            const float v1 = fqp<0xB1>(h[r]);
            const float v2 = fqp<0x4E>(h[r]);
            const float v3 = fqp<0x1B>(h[r]);
#pragma unroll
            for (int i = 0; i < 5; ++i) {
                acc[i] = fmaf(w[i][r][0], v0, acc[i]);
                acc[i] = fmaf(w[i][r][1], v1, acc[i]);
                acc[i] = fmaf(w[i][r][2], v2, acc[i]);
                acc[i] = fmaf(w[i][r][3], v3, acc[i]);
            }
        }
        float p0 = 0.f, p1 = 0.f;
#pragma unroll
        for (int i = 0; i < 5; ++i) {
            const float hn = fast_tanh(acc[i]);
            h[i] = hn;
            const float dm = hn * m[i];
            p0 = fmaf(dm, wo0[i], p0);
            p1 = fmaf(dm, wo1[i], p1);
        }
        p0 += fqp<0xB1>(p0);
        p0 += fqp<0x4E>(p0);
        p1 += fqp<0xB1>(p1);
        p1 += fqp<0x4E>(p1);
        if (sub == 0)
            *(float2*)&lds_o[gl * (kCT * kO) + j * kO] =
                make_float2(p0 + bo0, p1 + bo1);
    };

    auto flush_out = [&](int c) {
        {
            const int j  = tidx;
            const int gq = j / 5, wq = j - gq * 5;
            const float2 v = *(const float2*)&lds_o[gq * (kCT * kO) + wq * kO];
            *(float2*)(out + (g0 + gq) * (kT * kO) + c * (kCT * kO) + wq * kO) = v;
        }
        if (tidx < 64) {
            const int j  = 256 + tidx;
            const int gq = j / 5, wq = j - gq * 5;
            const float2 v = *(const float2*)&lds_o[gq * (kCT * kO) + wq * kO];
            *(float2*)(out + (g0 + gq) * (kT * kO) + c * (kCT * kO) + wq * kO) = v;
        }
    };

    stage_mask(0);
    load_x(0);
    __syncthreads();   // staged chunk 0 visible (drains vmcnt)

    for (int c = 0; c < kNC; ++c) {
#pragma unroll
        for (int j = 0; j < kCT; ++j) step(j);
        __syncthreads();                 // chunk consumed; lds_o complete
        if (c + 1 < kNC) {
            stage_mask(c + 1);           // refill lds_m (disjoint from lds_o)
            load_x(c + 1);
        }
        flush_out(c);                    // coalesced out writeback
        __syncthreads();                 // staged chunk visible; lds_o free
    }
}

}  // namespace

extern "C" void kernel_launch(void* const* d_in, const int* in_sizes, int n_in,
                              void* d_out, int out_size, void* d_ws, size_t ws_size,
                              hipStream_t stream) {
    const float* x     = (const float*)d_in[0];
    const float* W_ih  = (const float*)d_in[1];
    const float* W_hh  = (const float*)d_in[2];
    const float* b_ih  = (const float*)d_in[3];
    const float* b_hh  = (const float*)d_in[4];
    const float* W_out = (const float*)d_in[5];
    const float* b_out = (const float*)d_in[6];
    const float* mask  = (const float*)d_in[7];
    float* out = (float*)d_out;

    dim3 block(256);
    dim3 grid(kB / kGB);                 // 1024 blocks
    dprnn_kernel<<<grid, block, 0, stream>>>(x, W_ih, W_hh, b_ih, b_hh,
                                             W_out, b_out, mask, out);
}